// Round 4
// baseline (335.348 us; speedup 1.0000x reference)
//
#include <hip/hip_runtime.h>
#include <hip/hip_bf16.h>
#include <math.h>

// Problem constants
#define BATCH 64
#define SEQ   512
#define DIM   768
#define NW    256              // MAX_WORDS
#define NT    (BATCH * NW)     // 16384 tokens
#define KDIM  1536             // 2*DIM
#define HID   256              // router hidden
#define NL    7                // num labels
#define BK    64               // w1t K-tile (layout from prep)
#define NKT   (KDIM / BK)      // 24

#define TPB   512              // fused block size (8 waves)
#define TPW   16               // tokens (words) per block
#define XSP   1544             // Xs row stride (bf16): 1536 + 8 pad (2-way banks)

typedef __bf16 bf16_t;
typedef bf16_t bf16x4 __attribute__((ext_vector_type(4)));
typedef bf16_t bf16x8 __attribute__((ext_vector_type(8)));
typedef float  f32x4  __attribute__((ext_vector_type(4)));

// ---------------------------------------------------------------------------
// Kernel 1 (prep): convert router_w1 -> bf16 K-major tiles AND build the
// starts table. blocks 0..191 = w1 convert; blocks 192..319 = starts.
// w1t layout: w1t[kc][col][k] = W1[kc*64+k][col]  (col=0..255, k=0..63)
// ---------------------------------------------------------------------------
__global__ __launch_bounds__(256) void prep_kernel(
    const float* __restrict__ w1, bf16_t* __restrict__ w1t,
    const int* __restrict__ idh, const int* __restrict__ idr,
    int* __restrict__ starts)
{
    if (blockIdx.x < 192) {
        int kc = blockIdx.x >> 3;        // 0..23
        int kg = blockIdx.x & 7;         // 0..7
        int n  = threadIdx.x;            // 0..255
        bf16x8 v;
        #pragma unroll
        for (int j = 0; j < 8; j++)
            v[j] = (bf16_t)w1[(size_t)(kc * 64 + kg * 8 + j) * HID + n];
        *(bf16x8*)(w1t + (size_t)kc * (HID * BK) + n * BK + kg * 8) = v;
    } else {
        int blk = blockIdx.x - 192;      // 0..127 = 2 tensors x 64 batches
        int t = blk >> 6;
        int b = blk & 63;
        const int* ids = (t ? idr : idh) + b * SEQ;
        int w = threadIdx.x;
        int lo = 0, hi = SEQ;
        while (lo < hi) {
            int m = (lo + hi) >> 1;
            if (ids[m] < w) lo = m + 1; else hi = m;
        }
        int* row = starts + blk * 257;
        row[w] = lo;
        if (w == 0) row[256] = SEQ;
    }
}

// ---------------------------------------------------------------------------
// Kernel 2 (FUSED): align + router GEMM + alpha + blend + head + l2.
//
// R3 post-mortem: 4 structurally different standalone align kernels all hit
// 85-98 us (concurrency x latency cap), while total - align = 194 us has
// been CONSTANT across all rounds -> the split pipeline's fixed costs (X
// round-trip: 50 MB write + 100 MB re-read, plus 2 extra launches) are the
// remaining lever.  This kernel eliminates X entirely:
//
//   block = 16 tokens of one batch (grid 1024 x 512, 8 waves):
//   P1 gather: wave wv owns words {2wv, 2wv+1}; per word x tensor, lane
//      accumulates 3 f32x4 cells (c = lane, lane+64, lane+128) over the
//      word's subtoken rows -> mean -> bf16 into LDS Xs[16][1536+pad].
//      3 independent load chains/thread, static cell count -> real ILP.
//   P2 GEMM: 16x16x32 MFMA, A = Xs rows (LDS), B read DIRECTLY from
//      L2-resident w1t (layout matches B-frag: addr = kc*16384 + col*64 +
//      k2*32 + quad*8; 64-B sectors fully consumed).  48 K-steps, wave wv
//      covers hidden cols [wv*32, wv*32+32).
//   P3 alpha: relu+dot(w2) per token, shfl-reduce over col lanes, LDS
//      atomic across waves, sigmoid, broadcast + global store.
//   P4 blend: 32 lanes/token x 24 dims from Xs; logits via LDS-staged
//      head_w^T; l2 = ||hh-hr||; shfl-reduce width 32.
// ---------------------------------------------------------------------------
__global__ __launch_bounds__(TPB, 4) void fused_kernel(
    const float* __restrict__ hh, const float* __restrict__ hr,
    const int* __restrict__ starts, const bf16_t* __restrict__ w1t,
    const float* __restrict__ b1, const float* __restrict__ w2,
    const float* __restrict__ b2, const float* __restrict__ hw,
    const float* __restrict__ hb, float* __restrict__ out)
{
    __shared__ __align__(16) bf16_t Xs[TPW][XSP];   // 48.25 KB
    __shared__ float hws[NL * DIM];                 // 21 KB  [l][d]
    __shared__ float alpha_acc[TPW];
    __shared__ float alpha_s[TPW];

    int tid  = threadIdx.x;
    int lane = tid & 63;
    int wv   = tid >> 6;                 // 0..7
    int b    = blockIdx.x >> 4;          // batch
    int wb   = blockIdx.x & 15;          // 16-word block within batch
    int tok0 = b * NW + wb * TPW;        // global token base

    // stage head weights transposed (overlaps gather's global loads)
    for (int i = tid; i < DIM * NL; i += TPB) {
        int d = i / NL, l = i - d * NL;
        hws[l * DIM + d] = hw[i];
    }
    if (tid < TPW) alpha_acc[tid] = 0.f;

    // ---------------- P1: gather (segment-mean -> LDS) ----------------
    #pragma unroll
    for (int wi = 0; wi < 2; wi++) {
        int wl = wv * 2 + wi;            // local word 0..15 (wave-uniform)
        int w  = wb * TPW + wl;          // global word
        #pragma unroll
        for (int tt = 0; tt < 2; tt++) {
            const int* st = starts + (tt * 64 + b) * 257;
            int lo = __builtin_amdgcn_readfirstlane(st[w]);
            int n  = __builtin_amdgcn_readfirstlane(st[w + 1]) - lo;
            const f32x4* src = (const f32x4*)((tt ? hr : hh)
                                + (size_t)b * SEQ * DIM) + lane;
            f32x4 a0 = {0.f,0.f,0.f,0.f}, a1 = a0, a2 = a0;
            for (int s = lo; s < lo + n; s++) {
                const f32x4* r = src + (size_t)s * 192;
                a0 += r[0]; a1 += r[64]; a2 += r[128];
            }
            float inv = n > 0 ? 1.0f / (float)n : 0.0f;
            bf16x4 o0, o1, o2;
            #pragma unroll
            for (int e = 0; e < 4; e++) {
                o0[e] = (bf16_t)(a0[e] * inv);
                o1[e] = (bf16_t)(a1[e] * inv);
                o2[e] = (bf16_t)(a2[e] * inv);
            }
            bf16_t* xr = &Xs[wl][tt * DIM];
            *(bf16x4*)(xr + lane * 4)         = o0;
            *(bf16x4*)(xr + (lane + 64) * 4)  = o1;
            *(bf16x4*)(xr + (lane + 128) * 4) = o2;
        }
    }
    __syncthreads();

    // ---------------- P2: router GEMM (MFMA), B direct from w1t ----------------
    int row16 = lane & 15;
    int quad  = lane >> 4;
    f32x4 acc0 = {0.f,0.f,0.f,0.f}, acc1 = acc0;
    int col0 = wv * 32 + row16;          // ni=0 column
    #pragma unroll 2
    for (int ks = 0; ks < 48; ks++) {
        int kc = ks >> 1, k2 = ks & 1;
        bf16x8 af = *(const bf16x8*)(&Xs[row16][ks * 32 + quad * 8]);
        const bf16_t* bp = w1t + (size_t)kc * (HID * BK) + k2 * 32 + quad * 8;
        bf16x8 bf0 = *(const bf16x8*)(bp + (size_t)col0 * BK);
        bf16x8 bf1 = *(const bf16x8*)(bp + (size_t)(col0 + 16) * BK);
        acc0 = __builtin_amdgcn_mfma_f32_16x16x32_bf16(af, bf0, acc0, 0, 0, 0);
        acc1 = __builtin_amdgcn_mfma_f32_16x16x32_bf16(af, bf1, acc1, 0, 0, 0);
    }

    // ---------------- P3: alpha ----------------
    {
        float w2v0 = w2[col0],     b1v0 = b1[col0];
        float w2v1 = w2[col0 + 16], b1v1 = b1[col0 + 16];
        #pragma unroll
        for (int r = 0; r < 4; r++) {
            float v0 = acc0[r] + b1v0; v0 = v0 > 0.f ? v0 : 0.f;
            float v1 = acc1[r] + b1v1; v1 = v1 > 0.f ? v1 : 0.f;
            float p = v0 * w2v0 + v1 * w2v1;
            p += __shfl_xor(p, 1);
            p += __shfl_xor(p, 2);
            p += __shfl_xor(p, 4);
            p += __shfl_xor(p, 8);
            if (row16 == 0)
                atomicAdd(&alpha_acc[quad * 4 + r], p);   // token = quad*4+r
        }
    }
    __syncthreads();
    if (tid < TPW) {
        float a = 1.f / (1.f + expf(-(alpha_acc[tid] + b2[0])));
        alpha_s[tid] = a;
        out[(size_t)NT * NL + tok0 + tid] = a;
    }
    __syncthreads();

    // ---------------- P4: blend + head + l2 ----------------
    {
        int tl = wv * 2 + (lane >> 5);   // local token 0..15
        int u  = lane & 31;              // 32 lanes per token
        float a = alpha_s[tl];

        float lg[NL] = {0.f, 0.f, 0.f, 0.f, 0.f, 0.f, 0.f};
        float l2 = 0.f;

        #pragma unroll
        for (int g3 = 0; g3 < 3; g3++) {
            int d0 = u * 24 + g3 * 8;    // dims [u*24, u*24+24)
            bf16x8 hp = *(const bf16x8*)(&Xs[tl][d0]);
            bf16x8 rp = *(const bf16x8*)(&Xs[tl][DIM + d0]);
            float bl[8];
            #pragma unroll
            for (int e = 0; e < 8; e++) {
                float hhv = (float)hp[e];
                float hrv = (float)rp[e];
                float df  = hhv - hrv;
                bl[e] = fmaf(a, df, hrv);
                l2 = fmaf(df, df, l2);
            }
            #pragma unroll
            for (int l = 0; l < NL; l++) {
                f32x4 wA = *(const f32x4*)(&hws[l * DIM + d0]);
                f32x4 wB = *(const f32x4*)(&hws[l * DIM + d0 + 4]);
                lg[l] += bl[0]*wA[0] + bl[1]*wA[1] + bl[2]*wA[2] + bl[3]*wA[3]
                       + bl[4]*wB[0] + bl[5]*wB[1] + bl[6]*wB[2] + bl[7]*wB[3];
            }
        }

        #pragma unroll
        for (int off = 1; off < 32; off <<= 1) {
            #pragma unroll
            for (int l = 0; l < NL; l++) lg[l] += __shfl_xor(lg[l], off);
            l2 += __shfl_xor(l2, off);
        }

        int tok = tok0 + tl;
        if (u < NL) {
            float v = (u == 0) ? lg[0] : (u == 1) ? lg[1] : (u == 2) ? lg[2]
                    : (u == 3) ? lg[3] : (u == 4) ? lg[4] : (u == 5) ? lg[5] : lg[6];
            out[(size_t)tok * NL + u] = v + hb[u];
        } else if (u == NL) {
            out[(size_t)NT * NL + NT + tok] = sqrtf(l2);
        }
    }
}

// ---------------------------------------------------------------------------
extern "C" void kernel_launch(void* const* d_in, const int* in_sizes, int n_in,
                              void* d_out, int out_size, void* d_ws, size_t ws_size,
                              hipStream_t stream)
{
    const float* hh  = (const float*)d_in[0];
    const float* hr  = (const float*)d_in[1];
    const int*   idh = (const int*)d_in[2];
    const int*   idr = (const int*)d_in[3];
    const float* w1  = (const float*)d_in[5];
    const float* b1  = (const float*)d_in[6];
    const float* w2  = (const float*)d_in[7];
    const float* b2  = (const float*)d_in[8];
    const float* hw  = (const float*)d_in[9];
    const float* hb  = (const float*)d_in[10];
    float* out = (float*)d_out;

    bf16_t* w1t    = (bf16_t*)d_ws;                        // 786 KB
    int*    starts = (int*)(w1t + (size_t)NKT * HID * BK); // 132 KB

    prep_kernel<<<320, 256, 0, stream>>>(w1, w1t, idh, idr, starts);
    fused_kernel<<<BATCH * 16, TPB, 0, stream>>>(hh, hr, starts, w1t,
                                                 b1, w2, b2, hw, hb, out);
}

// Round 5
// 283.595 us; speedup vs baseline: 1.1825x; 1.1825x over previous
//
#include <hip/hip_runtime.h>
#include <hip/hip_bf16.h>
#include <math.h>

// Problem constants
#define BATCH 64
#define SEQ   512
#define DIM   768
#define NW    256              // MAX_WORDS
#define NT    (BATCH * NW)     // 16384 tokens
#define KDIM  1536             // 2*DIM
#define HID   256              // router hidden
#define NL    7                // num labels

// GEMM tiling
#define BM  32
#define BK  64
#define BKP 72                 // padded LDS row stride (bf16) -> 144 B
#define NKT (KDIM / BK)        // 24

typedef __bf16 bf16_t;
typedef bf16_t bf16x4 __attribute__((ext_vector_type(4)));
typedef bf16_t bf16x8 __attribute__((ext_vector_type(8)));
typedef float  f32x4  __attribute__((ext_vector_type(4)));

// ---------------------------------------------------------------------------
// Kernel 1 (prep): convert router_w1 -> bf16 K-major tiles AND build the
// starts table. blocks 0..191 = w1 convert; blocks 192..319 = starts.
// ---------------------------------------------------------------------------
__global__ __launch_bounds__(256) void prep_kernel(
    const float* __restrict__ w1, bf16_t* __restrict__ w1t,
    const int* __restrict__ idh, const int* __restrict__ idr,
    int* __restrict__ starts)
{
    if (blockIdx.x < 192) {
        int kc = blockIdx.x >> 3;        // 0..23
        int kg = blockIdx.x & 7;         // 0..7
        int n  = threadIdx.x;            // 0..255
        bf16x8 v;
        #pragma unroll
        for (int j = 0; j < 8; j++)
            v[j] = (bf16_t)w1[(size_t)(kc * 64 + kg * 8 + j) * HID + n];
        *(bf16x8*)(w1t + (size_t)kc * (HID * BK) + n * BK + kg * 8) = v;
    } else {
        int blk = blockIdx.x - 192;      // 0..127 = 2 tensors x 64 batches
        int t = blk >> 6;
        int b = blk & 63;
        const int* ids = (t ? idr : idh) + b * SEQ;
        int w = threadIdx.x;
        int lo = 0, hi = SEQ;
        while (lo < hi) {
            int m = (lo + hi) >> 1;
            if (ids[m] < w) lo = m + 1; else hi = m;
        }
        int* row = starts + blk * 257;
        row[w] = lo;
        if (w == 0) row[256] = SEQ;
    }
}

// ---------------------------------------------------------------------------
// Kernel 2: segment-mean align — FULL-ROW WAVE-TASK version.
//
// R4 post-mortem: four align variants converge at ~2.2 TB/s logical; the one
// untested invariant is the access SHAPE: every prior variant split each
// 3 KB row into 1 KB column chunks -> dominant read stream = 1 KB bursts
// strided by 3 KB (never sequential).  This version: one WAVE per
// (b, tensor, word) = 32768 wave-tasks.  A wave reads its word's rows as one
// CONTIGUOUS stream (3 x dwordx4 per lane per row; rows of a word are
// adjacent), i.e. ~6 KB sequential per task, 3 independent accumulate
// chains per lane, then one contiguous 1.5 KB bf16 store.  No LDS, small
// VGPR -> full 8 waves/SIMD occupancy.
// ---------------------------------------------------------------------------
__global__ __launch_bounds__(256) void align_kernel(
    const float* __restrict__ hh, const float* __restrict__ hr,
    const int* __restrict__ starts, bf16_t* __restrict__ X)
{
    int tid  = threadIdx.x;
    int lane = tid & 63;
    int wv   = tid >> 6;
    int task = blockIdx.x * 4 + wv;      // 0..32767  (wave-uniform)
    int w    = task & 255;
    int t    = (task >> 8) & 1;
    int b    = task >> 9;

    const int* st = starts + (t * 64 + b) * 257;
    int lo = __builtin_amdgcn_readfirstlane(st[w]);
    int hi = __builtin_amdgcn_readfirstlane(st[w + 1]);
    int n  = hi - lo;

    const f32x4* src = (const f32x4*)((t ? hr : hh) + (size_t)b * SEQ * DIM) + lane;
    bf16_t*      xr  = X + (size_t)b * NW * KDIM + (size_t)w * KDIM + t * DIM;

    f32x4 a0 = {0.f,0.f,0.f,0.f}, a1 = a0, a2 = a0;
    for (int s = lo; s < hi; s++) {
        const f32x4* r = src + (size_t)s * 192;
        f32x4 v0 = r[0];
        f32x4 v1 = r[64];
        f32x4 v2 = r[128];
        a0 += v0; a1 += v1; a2 += v2;
    }
    float inv = n > 0 ? 1.0f / (float)n : 0.0f;
    bf16x4 o0, o1, o2;
    #pragma unroll
    for (int e = 0; e < 4; e++) {
        o0[e] = (bf16_t)(a0[e] * inv);
        o1[e] = (bf16_t)(a1[e] * inv);
        o2[e] = (bf16_t)(a2[e] * inv);
    }
    *(bf16x4*)(xr + lane * 4)         = o0;
    *(bf16x4*)(xr + (lane + 64) * 4)  = o1;
    *(bf16x4*)(xr + (lane + 128) * 4) = o2;
}

// ---------------------------------------------------------------------------
// Kernel 3 (FUSED): router GEMM -> alpha -> blend + head + l2.
// GEMM part identical to the verified gemm_alpha_kernel; after alpha, the
// same block runs the verified blend phase on its own 32 tokens, re-reading
// X from L2 (the GEMM staging just fetched those bytes) — saves one launch
// and the 50 MB HBM re-read of X.  hws (head weights, 21.5 KB) reuses the
// dead Ws LDS region after the GEMM loop, keeping LDS at ~41.8 KB so
// occupancy stays at 3 blocks/CU.
// ---------------------------------------------------------------------------
__global__ __launch_bounds__(256) void gemm_blend_kernel(
    const bf16_t* __restrict__ X, const bf16_t* __restrict__ w1t,
    const float* __restrict__ b1, const float* __restrict__ w2,
    const float* __restrict__ b2, const float* __restrict__ hw,
    const float* __restrict__ hb, float* __restrict__ out)
{
    __shared__ __align__(16) unsigned char smem[4608 + 36864];
    bf16_t (*Xs)[BKP] = (bf16_t (*)[BKP])smem;               // 32 x 72 bf16
    bf16_t (*Ws)[BKP] = (bf16_t (*)[BKP])(smem + 4608);      // 256 x 72 bf16
    float*  hws       = (float*)(smem + 4608);               // reuses Ws region
    __shared__ float alpha_acc[BM];
    __shared__ float alpha_s[BM];

    int tid   = threadIdx.x;
    int lane  = tid & 63;
    int wv    = tid >> 6;
    int row16 = lane & 15;
    int quad  = lane >> 4;
    int tok0  = blockIdx.x * BM;

    f32x4 acc[2][4];
    #pragma unroll
    for (int mi = 0; mi < 2; mi++)
        #pragma unroll
        for (int ni = 0; ni < 4; ni++)
            acc[mi][ni] = (f32x4){0.f, 0.f, 0.f, 0.f};

    int xr = tid >> 3;
    int xc = tid & 7;

    for (int kc = 0; kc < NKT; kc++) {
        {
            const uint4* src = (const uint4*)(X + (size_t)(tok0 + xr) * KDIM + kc * BK + xc * 8);
            *(uint4*)(&Xs[xr][xc * 8]) = *src;
        }
        {
            const uint4* srcb = (const uint4*)(w1t + (size_t)kc * (HID * BK));
            #pragma unroll
            for (int i = 0; i < 8; i++) {
                int cidx = tid + i * 256;
                *(uint4*)(&Ws[cidx >> 3][(cidx & 7) * 8]) = srcb[cidx];
            }
        }
        __syncthreads();
        #pragma unroll
        for (int kk2 = 0; kk2 < 2; kk2++) {
            bf16x8 af[2], bfg[4];
            #pragma unroll
            for (int mi = 0; mi < 2; mi++)
                af[mi] = *(const bf16x8*)(&Xs[mi * 16 + row16][kk2 * 32 + quad * 8]);
            #pragma unroll
            for (int ni = 0; ni < 4; ni++)
                bfg[ni] = *(const bf16x8*)(&Ws[wv * 64 + ni * 16 + row16][kk2 * 32 + quad * 8]);
            #pragma unroll
            for (int mi = 0; mi < 2; mi++)
                #pragma unroll
                for (int ni = 0; ni < 4; ni++)
                    acc[mi][ni] = __builtin_amdgcn_mfma_f32_16x16x32_bf16(
                        af[mi], bfg[ni], acc[mi][ni], 0, 0, 0);
        }
        __syncthreads();
    }

    // ---------------- alpha reduction ----------------
    float w2v[4], b1v[4];
    #pragma unroll
    for (int ni = 0; ni < 4; ni++) {
        int col = wv * 64 + ni * 16 + row16;
        w2v[ni] = w2[col];
        b1v[ni] = b1[col];
    }
    if (tid < BM) alpha_acc[tid] = 0.f;
    __syncthreads();

    #pragma unroll
    for (int mi = 0; mi < 2; mi++) {
        #pragma unroll
        for (int r = 0; r < 4; r++) {
            float p = 0.f;
            #pragma unroll
            for (int ni = 0; ni < 4; ni++) {
                float v = acc[mi][ni][r] + b1v[ni];
                v = v > 0.f ? v : 0.f;
                p += v * w2v[ni];
            }
            p += __shfl_xor(p, 1);
            p += __shfl_xor(p, 2);
            p += __shfl_xor(p, 4);
            p += __shfl_xor(p, 8);
            if (row16 == 0)
                atomicAdd(&alpha_acc[mi * 16 + quad * 4 + r], p);
        }
    }

    // stage head weights into the dead Ws region (Ws last read before the
    // final __syncthreads of the GEMM loop)
    for (int i = tid; i < DIM * NL; i += 256) {
        int d = i / NL, l = i - d * NL;
        hws[l * DIM + d] = hw[i];
    }
    __syncthreads();                      // alpha_acc final + hws staged

    if (tid < BM) {
        float a = 1.f / (1.f + expf(-(alpha_acc[tid] + b2[0])));
        alpha_s[tid] = a;
        out[(size_t)NT * NL + tok0 + tid] = a;
    }
    __syncthreads();                      // alpha_s visible

    // ---------------- blend + head + l2 (verified R3 structure) ----------------
    {
        int g   = lane >> 3;
        int u   = lane & 7;
        int tl  = wv * 8 + g;             // local token 0..31
        int tok = tok0 + tl;
        float a = alpha_s[tl];
        const bf16_t* xrow = X + (size_t)tok * KDIM;   // L2-hot (staged above)

        float lg[NL] = {0.f, 0.f, 0.f, 0.f, 0.f, 0.f, 0.f};
        float l2 = 0.f;

        #pragma unroll
        for (int k = 0; k < 12; k++) {
            int d0 = (k * 8 + u) * 8;
            bf16x8 hp = *(const bf16x8*)(xrow + d0);
            bf16x8 rp = *(const bf16x8*)(xrow + DIM + d0);
            float bl[8];
            #pragma unroll
            for (int e = 0; e < 8; e++) {
                float hhv = (float)hp[e];
                float hrv = (float)rp[e];
                float df  = hhv - hrv;
                bl[e] = fmaf(a, df, hrv);
                l2 = fmaf(df, df, l2);
            }
            #pragma unroll
            for (int l = 0; l < NL; l++) {
                f32x4 wA = *(const f32x4*)(&hws[l * DIM + d0]);
                f32x4 wB = *(const f32x4*)(&hws[l * DIM + d0 + 4]);
                lg[l] += bl[0]*wA[0] + bl[1]*wA[1] + bl[2]*wA[2] + bl[3]*wA[3]
                       + bl[4]*wB[0] + bl[5]*wB[1] + bl[6]*wB[2] + bl[7]*wB[3];
            }
        }

        #pragma unroll
        for (int off = 1; off < 8; off <<= 1) {
            #pragma unroll
            for (int l = 0; l < NL; l++) lg[l] += __shfl_xor(lg[l], off);
            l2 += __shfl_xor(l2, off);
        }

        if (u < NL) {
            float v = (u == 0) ? lg[0] : (u == 1) ? lg[1] : (u == 2) ? lg[2]
                    : (u == 3) ? lg[3] : (u == 4) ? lg[4] : (u == 5) ? lg[5] : lg[6];
            out[(size_t)tok * NL + u] = v + hb[u];
        } else {
            out[(size_t)NT * NL + NT + tok] = sqrtf(l2);
        }
    }
}

// ---------------------------------------------------------------------------
extern "C" void kernel_launch(void* const* d_in, const int* in_sizes, int n_in,
                              void* d_out, int out_size, void* d_ws, size_t ws_size,
                              hipStream_t stream)
{
    const float* hh  = (const float*)d_in[0];
    const float* hr  = (const float*)d_in[1];
    const int*   idh = (const int*)d_in[2];
    const int*   idr = (const int*)d_in[3];
    const float* w1  = (const float*)d_in[5];
    const float* b1  = (const float*)d_in[6];
    const float* w2  = (const float*)d_in[7];
    const float* b2  = (const float*)d_in[8];
    const float* hw  = (const float*)d_in[9];
    const float* hb  = (const float*)d_in[10];
    float* out = (float*)d_out;

    bf16_t* X      = (bf16_t*)d_ws;                        // 50.33 MB
    bf16_t* w1t    = X + (size_t)NT * KDIM;                // 0.79 MB (tiled)
    int*    starts = (int*)(w1t + (size_t)NKT * HID * BK); // 132 KB

    prep_kernel<<<320, 256, 0, stream>>>(w1, w1t, idh, idr, starts);
    align_kernel<<<8192, 256, 0, stream>>>(hh, hr, starts, X);
    gemm_blend_kernel<<<NT / BM, 256, 0, stream>>>(X, w1t, b1, w2, b2,
                                                   hw, hb, out);
}